// Round 7
// baseline (347.197 us; speedup 1.0000x reference)
//
#include <hip/hip_runtime.h>
#include <math.h>

#define B_SZ  8192
#define KD    256
#define NCLS  32
#define NCHUNK 8          // j-chunks per i-row of tiles
#define JTPC   4          // 256-wide j-tiles per block
#define NJT    32         // total 256-wide j-tiles
#define SQRT_INVT 3.16227766016838f   // sqrt(10): fold 1/T into normalized rows

typedef __attribute__((ext_vector_type(8))) short short8;
typedef __attribute__((ext_vector_type(4))) float f32x4;

static __device__ __forceinline__ unsigned short f2bf(float f) {
    unsigned u = __float_as_uint(f);
    return (unsigned short)((u + 0x7FFF + ((u >> 16) & 1)) >> 16);   // RNE
}
static __device__ __forceinline__ float bf2f(unsigned short h) {
    return __uint_as_float((unsigned)h << 16);
}

// ---------------- kernel 1: normalize+scale rows, emit combined [hi(256)|lo(256)] bf16 ----------------
__global__ void prep_kernel(const float* __restrict__ feat, unsigned short* __restrict__ Fhl) {
    int row  = blockIdx.x * 4 + (threadIdx.x >> 6);
    int lane = threadIdx.x & 63;
    const float4 v = ((const float4*)(feat + (size_t)row * KD))[lane];
    float s = v.x * v.x + v.y * v.y + v.z * v.z + v.w * v.w;
    #pragma unroll
    for (int off = 1; off < 64; off <<= 1) s += __shfl_xor(s, off, 64);
    float rn = rsqrtf(s) * SQRT_INVT;
    float fn[4] = {v.x * rn, v.y * rn, v.z * rn, v.w * rn};
    ushort4 hi, lo;
    unsigned short* hp = (unsigned short*)&hi;
    unsigned short* lp = (unsigned short*)&lo;
    #pragma unroll
    for (int e = 0; e < 4; e++) {
        unsigned short h = f2bf(fn[e]);
        hp[e] = h;
        lp[e] = f2bf(fn[e] - bf2f(h));
    }
    ((ushort4*)(Fhl + (size_t)row * 512))[lane]      = hi;   // cols 0..255  = hi
    ((ushort4*)(Fhl + (size_t)row * 512 + 256))[lane] = lo;  // cols 256..511 = lo
}

// ---------------- kernel 2: global per-class counts ----------------
__global__ void count_kernel(const int* __restrict__ labels, int* __restrict__ counts) {
    __shared__ int sc[NCLS];
    int t = threadIdx.x;
    if (t < NCLS) sc[t] = 0;
    __syncthreads();
    for (int i = t; i < B_SZ; i += 256) atomicAdd(&sc[labels[i]], 1);
    __syncthreads();
    if (t < NCLS) counts[t] = sc[t];
}

// ---------------- kernel 3: barrier-free direct-to-register sim GEMM + MFMA class reduce ----------------
// 256 blocks (1/CU), 512 threads = 8 waves 2(row)x4(col); wave owns 128x64 of C.
// Fragments loaded straight from global (L1/L2-resident working set); NO LDS staging, NO K-loop barriers.
__global__ __launch_bounds__(512, 2) void sim_kernel(
    const unsigned short* __restrict__ Fhl, const int* __restrict__ labels,
    float* __restrict__ pcls, float* __restrict__ ppos)
{
    __shared__ __align__(16) char sE_raw[256 * 512];   // 128KB: [256 i][512B] bf16, XOR-swizzled
    __shared__ int   slab[256];
    __shared__ float spos[256];

    const int bid = blockIdx.x;
    const int swz = (bid & 7) * 32 + (bid >> 3);   // bijective XCD swizzle (256 % 8 == 0)
    const int itile = swz >> 3;
    const int jc    = swz & 7;
    const int i0    = itile * 256;

    const int t    = threadIdx.x;
    const int wave = t >> 6;
    const int lane = t & 63;
    const int wr   = wave >> 2;      // 0..1 -> 128-row half
    const int wc   = wave & 3;       // 0..3 -> 64-col quarter
    const int l15  = lane & 15;
    const int l4   = lane >> 4;

    if (t < 256) spos[t] = 0.0f;

    int labi[8];
    #pragma unroll
    for (int m = 0; m < 8; m++) labi[m] = labels[i0 + wr * 128 + m * 16 + l15];

    // wave-local operand bases (lane-resolved row, k-slice column)
    const unsigned short* Abase = Fhl + (size_t)(i0 + wr * 128 + l15) * 512 + l4 * 8;

    #pragma unroll 1
    for (int jt = jc * JTPC; jt < (jc + 1) * JTPC; ++jt) {
        const int j0 = jt * 256;
        if (t < 256) slab[t] = labels[j0 + t];

        const unsigned short* Bbase = Fhl + (size_t)(j0 + wc * 64 + l15) * 512 + l4 * 8;

        f32x4 acc[8][4];
        #pragma unroll
        for (int m = 0; m < 8; m++)
            #pragma unroll
            for (int n = 0; n < 4; n++)
                acc[m][n] = (f32x4){0.f, 0.f, 0.f, 0.f};

        // ---- barrier-free K-loop: 8 steps of K=32; frags direct from global ----
        #pragma unroll 1
        for (int ks = 0; ks < 8; ++ks) {
            const int kc = ks * 32;
            short8 bh[4], bl[4];
            #pragma unroll
            for (int n = 0; n < 4; ++n) {
                const unsigned short* p = Bbase + (size_t)(n * 16) * 512 + kc;
                bh[n] = *(const short8*)p;
                bl[n] = *(const short8*)(p + 256);
            }
            short8 ah0[4], al0[4], ah1[4], al1[4];
            #pragma unroll
            for (int mm = 0; mm < 4; ++mm) {
                const unsigned short* p = Abase + (size_t)(mm * 16) * 512 + kc;
                ah0[mm] = *(const short8*)p;
                al0[mm] = *(const short8*)(p + 256);
            }
            #pragma unroll
            for (int mm = 0; mm < 4; ++mm) {
                const unsigned short* p = Abase + (size_t)((4 + mm) * 16) * 512 + kc;
                ah1[mm] = *(const short8*)p;
                al1[mm] = *(const short8*)(p + 256);
            }
            // swapped operands (q indexes j): products BhAh + BhAl + BlAh
            __builtin_amdgcn_s_setprio(1);
            #pragma unroll
            for (int mm = 0; mm < 4; ++mm)
                #pragma unroll
                for (int n = 0; n < 4; ++n) {
                    acc[mm][n] = __builtin_amdgcn_mfma_f32_16x16x32_bf16(bh[n], ah0[mm], acc[mm][n], 0, 0, 0);
                    acc[mm][n] = __builtin_amdgcn_mfma_f32_16x16x32_bf16(bh[n], al0[mm], acc[mm][n], 0, 0, 0);
                    acc[mm][n] = __builtin_amdgcn_mfma_f32_16x16x32_bf16(bl[n], ah0[mm], acc[mm][n], 0, 0, 0);
                }
            __builtin_amdgcn_s_setprio(0);
            __builtin_amdgcn_s_setprio(1);
            #pragma unroll
            for (int mm = 0; mm < 4; ++mm)
                #pragma unroll
                for (int n = 0; n < 4; ++n) {
                    acc[4 + mm][n] = __builtin_amdgcn_mfma_f32_16x16x32_bf16(bh[n], ah1[mm], acc[4 + mm][n], 0, 0, 0);
                    acc[4 + mm][n] = __builtin_amdgcn_mfma_f32_16x16x32_bf16(bh[n], al1[mm], acc[4 + mm][n], 0, 0, 0);
                    acc[4 + mm][n] = __builtin_amdgcn_mfma_f32_16x16x32_bf16(bl[n], ah1[mm], acc[4 + mm][n], 0, 0, 0);
                }
            __builtin_amdgcn_s_setprio(0);
        }

        __syncthreads();   // slab visible; previous jt's scr fully consumed

        // ---- epilogue: sim -> spos (rare atomics) + E=exp ----
        #pragma unroll
        for (int m = 0; m < 8; m++) {
            const int il = wr * 128 + m * 16 + l15;
            const int ig = i0 + il;
            #pragma unroll
            for (int n = 0; n < 4; n++) {
                const int jb = wc * 64 + n * 16 + l4 * 4;
                int4 lj = *(const int4*)&slab[jb];
                const int* ljp = (const int*)&lj;
                #pragma unroll
                for (int q = 0; q < 4; q++) {
                    const int jg = j0 + jb + q;
                    float sim = acc[m][n][q];            // already scaled by 1/T
                    bool self = (ig == jg);
                    if (!self && ljp[q] == labi[m]) atomicAdd(&spos[il], sim);
                    acc[m][n][q] = self ? 0.0f : __expf(sim);
                }
            }
        }

        // one-hot B-fragments over this wave's 64 j-cols (2 K=32 slices)
        short8 hf[2][2];
        #pragma unroll
        for (int kk = 0; kk < 2; kk++) {
            const int jb = wc * 64 + kk * 32 + l4 * 8;
            int4 lv0 = *(const int4*)&slab[jb];
            int4 lv1 = *(const int4*)&slab[jb + 4];
            int lv[8] = {lv0.x, lv0.y, lv0.z, lv0.w, lv1.x, lv1.y, lv1.z, lv1.w};
            #pragma unroll
            for (int cb = 0; cb < 2; cb++) {
                short8 h;
                #pragma unroll
                for (int e = 0; e < 8; e++)
                    h[e] = (lv[e] == cb * 16 + l15) ? (short)0x3F80 : (short)0;
                hf[kk][cb] = h;
            }
        }

        f32x4 acc_cs[8][2];
        #pragma unroll
        for (int m = 0; m < 8; m++)
            #pragma unroll
            for (int cb = 0; cb < 2; cb++)
                acc_cs[m][cb] = (f32x4){0.f, 0.f, 0.f, 0.f};

        char* sE = sE_raw;   // [256 i][512B], rows XOR-swizzled; wave-private (row,col) regions

        // copy 0: E-hi -> CS MFMA; copy 1: E-lo -> CS MFMA
        #pragma unroll
        for (int copy = 0; copy < 2; copy++) {
            #pragma unroll
            for (int m = 0; m < 8; m++) {
                const int row = wr * 128 + m * 16 + l15;
                #pragma unroll
                for (int n = 0; n < 4; n++) {
                    const int bc = (wc * 128 + n * 32 + l4 * 8) ^ ((row & 7) << 4);
                    unsigned short b[4];
                    #pragma unroll
                    for (int q = 0; q < 4; q++) {
                        float e = acc[m][n][q];
                        unsigned short h = f2bf(e);
                        b[q] = copy == 0 ? h : f2bf(e - bf2f(h));
                    }
                    uint2 w;
                    w.x = (unsigned)b[0] | ((unsigned)b[1] << 16);
                    w.y = (unsigned)b[2] | ((unsigned)b[3] << 16);
                    *(uint2*)(sE + (size_t)row * 512 + bc) = w;
                }
            }
            #pragma unroll
            for (int m = 0; m < 8; m++) {
                const int row = wr * 128 + m * 16 + l15;
                #pragma unroll
                for (int kk = 0; kk < 2; kk++) {
                    const int bc = (wc * 128 + kk * 64 + l4 * 16) ^ ((row & 7) << 4);
                    short8 ef = *(const short8*)(sE + (size_t)row * 512 + bc);
                    #pragma unroll
                    for (int cb = 0; cb < 2; cb++)
                        acc_cs[m][cb] = __builtin_amdgcn_mfma_f32_16x16x32_bf16(
                            ef, hf[kk][cb], acc_cs[m][cb], 0, 0, 0);
                }
            }
        }

        // ---- deterministic cross-wave (wc) reduce via LDS, write per-tile partials ----
        __syncthreads();                 // all CS reads done; sE region reusable
        float* scr = (float*)sE_raw;     // [6][128][33] f32
        if (wc > 0) {
            const int idx = (wc - 1) * 2 + wr;
            #pragma unroll
            for (int m = 0; m < 8; m++)
                #pragma unroll
                for (int cb = 0; cb < 2; cb++)
                    #pragma unroll
                    for (int q = 0; q < 4; q++)
                        scr[((size_t)idx * 128 + m * 16 + l4 * 4 + q) * 33 + cb * 16 + l15] =
                            acc_cs[m][cb][q];
        }
        __syncthreads();
        if (wc == 0) {
            float* pc = pcls + (size_t)(itile * NJT + jt) * 256 * NCLS;
            #pragma unroll
            for (int m = 0; m < 8; m++)
                #pragma unroll
                for (int cb = 0; cb < 2; cb++)
                    #pragma unroll
                    for (int q = 0; q < 4; q++) {
                        const int r128 = m * 16 + l4 * 4 + q;
                        const int c    = cb * 16 + l15;
                        float v = acc_cs[m][cb][q];
                        #pragma unroll
                        for (int k = 0; k < 3; k++)
                            v += scr[((size_t)(k * 2 + wr) * 128 + r128) * 33 + c];
                        pc[(wr * 128 + r128) * NCLS + c] = v;
                    }
        }
        __syncthreads();   // scr consumed before next tile's sE writes
    }

    if (t < 256) ppos[(size_t)swz * 256 + t] = spos[t];
}

// ---------------- kernel 4: per-anchor loss (8 lanes per anchor) ----------------
__global__ void reduce_kernel(const float* __restrict__ pcls, const float* __restrict__ ppos,
                              const int* __restrict__ counts, const int* __restrict__ labels,
                              float* __restrict__ loss_i, float* __restrict__ validf) {
    int tid = blockIdx.x * blockDim.x + threadIdx.x;
    int i  = tid >> 3;
    int cq = tid & 7;
    if (i >= B_SZ) return;
    int itile = i >> 8, ilocal = i & 255;

    f32x4 cs = (f32x4){0.f, 0.f, 0.f, 0.f};
    for (int ch = 0; ch < NJT; ch++) {
        const float* p = pcls + ((size_t)(itile * NJT + ch) * 256 + ilocal) * NCLS + cq * 4;
        f32x4 v = *(const f32x4*)p;
        cs = cs + v;
    }
    int labi = labels[i];
    float dpart = 0.0f;
    #pragma unroll
    for (int e = 0; e < 4; e++) {
        int c = cq * 4 + e;
        int cnt = counts[c] - (c == labi ? 1 : 0);
        if (cnt > 0) dpart += cs[e] / (float)cnt;
    }
    #pragma unroll
    for (int off = 1; off < 8; off <<= 1) dpart += __shfl_xor(dpart, off, 64);

    if (cq == 0) {
        float psum = 0.0f;
        for (int ch = 0; ch < NCHUNK; ch++)
            psum += ppos[(size_t)(itile * NCHUNK + ch) * 256 + ilocal];
        int P = counts[labi] - 1;
        bool valid = P > 0;
        float li = 0.0f;
        if (valid) li = logf(fmaxf(dpart, 1e-30f)) - psum / (float)max(P, 1);
        loss_i[i] = li;
        validf[i] = valid ? 1.0f : 0.0f;
    }
}

// ---------------- kernel 5: deterministic final reduction ----------------
__global__ void final_kernel(const float* __restrict__ loss_i, const float* __restrict__ validf,
                             float* __restrict__ out) {
    __shared__ float ssum[256];
    __shared__ float scnt[256];
    int t = threadIdx.x;
    float s = 0.0f, c = 0.0f;
    for (int i = t; i < B_SZ; i += 256) { s += loss_i[i]; c += validf[i]; }
    ssum[t] = s; scnt[t] = c;
    __syncthreads();
    #pragma unroll
    for (int off = 128; off > 0; off >>= 1) {
        if (t < off) { ssum[t] += ssum[t + off]; scnt[t] += scnt[t + off]; }
        __syncthreads();
    }
    if (t == 0) out[0] = (scnt[0] > 0.0f) ? ssum[0] / scnt[0] : 0.0f;
}

// ---------------- launch ----------------
extern "C" void kernel_launch(void* const* d_in, const int* in_sizes, int n_in,
                              void* d_out, int out_size, void* d_ws, size_t ws_size,
                              hipStream_t stream) {
    const float* feat   = (const float*)d_in[0];
    const int*   labels = (const int*)d_in[1];
    float*       out    = (float*)d_out;

    char* ws = (char*)d_ws;
    size_t off = 0;
    auto alloc = [&](size_t bytes) -> void* {
        void* p = ws + off;
        off = (off + bytes + 255) & ~(size_t)255;
        return p;
    };

    unsigned short* Fhl = (unsigned short*)alloc((size_t)B_SZ * 512 * 2);     // 8.4MB
    int*   counts = (int*)alloc((size_t)NCLS * 4);
    float* loss_i = (float*)alloc((size_t)B_SZ * 4);
    float* validf = (float*)alloc((size_t)B_SZ * 4);
    float* ppos   = (float*)alloc((size_t)256 * 256 * 4);
    float* pcls   = (float*)alloc((size_t)32 * NJT * 256 * NCLS * 4);         // 32MB

    prep_kernel<<<B_SZ / 4, 256, 0, stream>>>(feat, Fhl);
    count_kernel<<<1, 256, 0, stream>>>(labels, counts);
    sim_kernel<<<256, 512, 0, stream>>>(Fhl, labels, pcls, ppos);
    reduce_kernel<<<B_SZ * 8 / 256, 256, 0, stream>>>(pcls, ppos, counts, labels, loss_i, validf);
    final_kernel<<<1, 256, 0, stream>>>(loss_i, validf, out);
}

// Round 8
// 157.456 us; speedup vs baseline: 2.2050x; 2.2050x over previous
//
#include <hip/hip_runtime.h>
#include <math.h>

#define B_SZ  8192
#define KD    256
#define NCLS  32
#define NCHUNK 8          // j-chunks per i-tile row; grid = 64*NCHUNK = 512 blocks
#define JTPC   8          // 128-wide j-tiles per block
#define SQRT_INVT 3.16227766016838f   // sqrt(10): fold 1/T into normalized rows

typedef __attribute__((ext_vector_type(8))) short short8;
typedef __attribute__((ext_vector_type(4))) float f32x4;

static __device__ __forceinline__ unsigned short f2bf(float f) {
    unsigned u = __float_as_uint(f);
    return (unsigned short)((u + 0x7FFF + ((u >> 16) & 1)) >> 16);   // RNE
}
static __device__ __forceinline__ float bf2f(unsigned short h) {
    return __uint_as_float((unsigned)h << 16);
}

// ---------------- kernel 1: normalize+scale rows, emit combined [hi(256)|lo(256)] bf16 ----------------
__global__ void prep_kernel(const float* __restrict__ feat, unsigned short* __restrict__ Fhl) {
    int row  = blockIdx.x * 4 + (threadIdx.x >> 6);
    int lane = threadIdx.x & 63;
    const float4 v = ((const float4*)(feat + (size_t)row * KD))[lane];
    float s = v.x * v.x + v.y * v.y + v.z * v.z + v.w * v.w;
    #pragma unroll
    for (int off = 1; off < 64; off <<= 1) s += __shfl_xor(s, off, 64);
    float rn = rsqrtf(s) * SQRT_INVT;
    float fn[4] = {v.x * rn, v.y * rn, v.z * rn, v.w * rn};
    ushort4 hi, lo;
    unsigned short* hp = (unsigned short*)&hi;
    unsigned short* lp = (unsigned short*)&lo;
    #pragma unroll
    for (int e = 0; e < 4; e++) {
        unsigned short h = f2bf(fn[e]);
        hp[e] = h;
        lp[e] = f2bf(fn[e] - bf2f(h));
    }
    ((ushort4*)(Fhl + (size_t)row * 512))[lane]       = hi;   // cols 0..255  = hi
    ((ushort4*)(Fhl + (size_t)row * 512 + 256))[lane] = lo;   // cols 256..511 = lo
}

// ---------------- kernel 2: global per-class counts ----------------
__global__ void count_kernel(const int* __restrict__ labels, int* __restrict__ counts) {
    __shared__ int sc[NCLS];
    int t = threadIdx.x;
    if (t < NCLS) sc[t] = 0;
    __syncthreads();
    for (int i = t; i < B_SZ; i += 256) atomicAdd(&sc[labels[i]], 1);
    __syncthreads();
    if (t < NCLS) counts[t] = sc[t];
}

// ---------------- kernel 3: 128x128-tile sim GEMM, 2 blocks/CU (m97 regime) + MFMA class reduce ----------------
// 512 blocks (2/CU), 256 threads = 4 waves in 2x2; wave owns 64x64 of C.
// BK=32 (hi+lo = 64 shorts/row): stage A[128][64sh] + B[128][64sh] = 32KB/step, dbuf 64KB.
__global__ __launch_bounds__(256, 2) void sim_kernel(
    const unsigned short* __restrict__ Fhl, const int* __restrict__ labels,
    float* __restrict__ pcls, float* __restrict__ ppos)
{
    __shared__ __align__(16) unsigned short sbuf[2][2][128 * 64];  // 64KB: [buf][A/B]
    __shared__ int   slab[128];
    __shared__ float spos[128];

    const int bid = blockIdx.x;
    const int swz = (bid & 7) * 64 + (bid >> 3);   // bijective XCD swizzle (512 % 8 == 0)
    const int itile = swz >> 3;                    // swz / NCHUNK
    const int jc    = swz & 7;                     // swz % NCHUNK
    const int i0    = itile * 128;

    const int t    = threadIdx.x;
    const int wave = t >> 6;
    const int lane = t & 63;
    const int wr   = wave >> 1;      // 0..1 -> 64-row half
    const int wc   = wave & 1;       // 0..1 -> 64-col half
    const int l15  = lane & 15;
    const int l4   = lane >> 4;

    if (t < 128) spos[t] = 0.0f;

    int labi[4];
    #pragma unroll
    for (int m = 0; m < 4; m++) labi[m] = labels[i0 + wr * 64 + m * 16 + l15];

    const int rT = t >> 3;    // row-within-32 staged per quarter
    const int s8 = t & 7;     // physical 16B slot

    auto STAGE = [&](int buf, int j0s, int kc) {
        #pragma unroll
        for (int a = 0; a < 4; ++a) {
            int r   = a * 32 + rT;
            int sl  = s8 ^ (r & 7);                         // logical slot (involution)
            int col = kc + (sl & 3) * 8 + ((sl & 4) << 6);  // slots 0-3 hi, 4-7 lo (+256)
            const unsigned short* gA = Fhl + (size_t)(i0 + r) * 512 + col;
            char* lA = (char*)&sbuf[buf][0][0] + a * 4096 + wave * 1024;
            __builtin_amdgcn_global_load_lds(
                (const __attribute__((address_space(1))) void*)gA,
                (__attribute__((address_space(3))) void*)lA, 16, 0, 0);
            const unsigned short* gB = Fhl + (size_t)(j0s + r) * 512 + col;
            char* lB = (char*)&sbuf[buf][1][0] + a * 4096 + wave * 1024;
            __builtin_amdgcn_global_load_lds(
                (const __attribute__((address_space(1))) void*)gB,
                (__attribute__((address_space(3))) void*)lB, 16, 0, 0);
        }
    };

    // persistent class sums across the block's 8 j-tiles: [m][cb], rows i, cols c
    f32x4 acc_cs[4][2];
    #pragma unroll
    for (int m = 0; m < 4; m++)
        #pragma unroll
        for (int cb = 0; cb < 2; cb++)
            acc_cs[m][cb] = (f32x4){0.f, 0.f, 0.f, 0.f};

    #pragma unroll 1
    for (int jt = jc * JTPC; jt < (jc + 1) * JTPC; ++jt) {
        const int j0 = jt * 128;

        __syncthreads();                    // prev tile's slab/sE reads fully done
        if (t < 128) slab[t] = labels[j0 + t];

        f32x4 acc[4][4];
        #pragma unroll
        for (int m = 0; m < 4; m++)
            #pragma unroll
            for (int n = 0; n < 4; n++)
                acc[m][n] = (f32x4){0.f, 0.f, 0.f, 0.f};

        STAGE(0, j0, 0);
        __syncthreads();                    // stage0 landed + slab visible

        // ---- 2-phase pipelined K-loop: 8 steps of BK=32, 3 products ----
        #pragma unroll 1
        for (int ks = 0; ks < 8; ++ks) {
            if (ks < 7) STAGE((ks + 1) & 1, j0, (ks + 1) * 32);
            const unsigned short* pA = &sbuf[ks & 1][0][0];
            const unsigned short* pB = &sbuf[ks & 1][1][0];
            short8 bh[4], bl[4];
            #pragma unroll
            for (int n = 0; n < 4; ++n) {
                int r = wc * 64 + n * 16 + l15;
                bh[n] = *(const short8*)&pB[r * 64 + ((l4 ^ (r & 7)) * 8)];
                bl[n] = *(const short8*)&pB[r * 64 + (((4 + l4) ^ (r & 7)) * 8)];
            }
            __builtin_amdgcn_s_setprio(1);
            #pragma unroll
            for (int m = 0; m < 4; ++m) {
                int r = wr * 64 + m * 16 + l15;
                short8 ah = *(const short8*)&pA[r * 64 + ((l4 ^ (r & 7)) * 8)];
                short8 al = *(const short8*)&pA[r * 64 + (((4 + l4) ^ (r & 7)) * 8)];
                #pragma unroll
                for (int n = 0; n < 4; ++n) {
                    // swapped operands: q indexes j. products: BhAh + BhAl + BlAh
                    acc[m][n] = __builtin_amdgcn_mfma_f32_16x16x32_bf16(bh[n], ah, acc[m][n], 0, 0, 0);
                    acc[m][n] = __builtin_amdgcn_mfma_f32_16x16x32_bf16(bh[n], al, acc[m][n], 0, 0, 0);
                    acc[m][n] = __builtin_amdgcn_mfma_f32_16x16x32_bf16(bl[n], ah, acc[m][n], 0, 0, 0);
                }
            }
            __builtin_amdgcn_s_setprio(0);
            __syncthreads();   // drains next stage; swaps buffers
        }

        // ---- epilogue: sim -> spos (rare atomics) + E=exp ----
        #pragma unroll
        for (int m = 0; m < 4; m++) {
            const int il = wr * 64 + m * 16 + l15;
            const int ig = i0 + il;
            #pragma unroll
            for (int n = 0; n < 4; n++) {
                const int jb = wc * 64 + n * 16 + l4 * 4;
                int4 lj = *(const int4*)&slab[jb];
                const int* ljp = (const int*)&lj;
                #pragma unroll
                for (int q = 0; q < 4; q++) {
                    const int jg = j0 + jb + q;
                    float sim = acc[m][n][q];            // already scaled by 1/T
                    bool self = (ig == jg);
                    if (!self && ljp[q] == labi[m]) atomicAdd(&spos[il], sim);
                    acc[m][n][q] = self ? 0.0f : __expf(sim);
                }
            }
        }

        // one-hot B-fragments over this wave's 64 j-cols (2 K=32 slices)
        short8 hf[2][2];
        #pragma unroll
        for (int kk = 0; kk < 2; kk++) {
            const int jb = wc * 64 + kk * 32 + l4 * 8;
            int4 lv0 = *(const int4*)&slab[jb];
            int4 lv1 = *(const int4*)&slab[jb + 4];
            int lv[8] = {lv0.x, lv0.y, lv0.z, lv0.w, lv1.x, lv1.y, lv1.z, lv1.w};
            #pragma unroll
            for (int cb = 0; cb < 2; cb++) {
                short8 h;
                #pragma unroll
                for (int e = 0; e < 8; e++)
                    h[e] = (lv[e] == cb * 16 + l15) ? (short)0x3F80 : (short)0;
                hf[kk][cb] = h;
            }
        }

        char* sE = (char*)&sbuf[1][0][0];   // 32KB: [128 i][256B] bf16, XOR-swizzled rows; wave-private patches

        // copy 0: E-hi -> CS MFMA; copy 1: E-lo -> CS MFMA (accumulate into persistent acc_cs)
        #pragma unroll
        for (int copy = 0; copy < 2; copy++) {
            #pragma unroll
            for (int m = 0; m < 4; m++) {
                const int row = wr * 64 + m * 16 + l15;
                #pragma unroll
                for (int n = 0; n < 4; n++) {
                    const int bc = (wc * 128 + n * 32 + l4 * 8) ^ ((row & 7) << 4);
                    unsigned short b[4];
                    #pragma unroll
                    for (int q = 0; q < 4; q++) {
                        float e = acc[m][n][q];
                        unsigned short h = f2bf(e);
                        b[q] = copy == 0 ? h : f2bf(e - bf2f(h));
                    }
                    uint2 w;
                    w.x = (unsigned)b[0] | ((unsigned)b[1] << 16);
                    w.y = (unsigned)b[2] | ((unsigned)b[3] << 16);
                    *(uint2*)(sE + (size_t)row * 256 + bc) = w;
                }
            }
            #pragma unroll
            for (int m = 0; m < 4; m++) {
                const int row = wr * 64 + m * 16 + l15;
                #pragma unroll
                for (int kk = 0; kk < 2; kk++) {
                    const int bc = (wc * 128 + kk * 64 + l4 * 16) ^ ((row & 7) << 4);
                    short8 ef = *(const short8*)(sE + (size_t)row * 256 + bc);
                    #pragma unroll
                    for (int cb = 0; cb < 2; cb++)
                        acc_cs[m][cb] = __builtin_amdgcn_mfma_f32_16x16x32_bf16(
                            ef, hf[kk][cb], acc_cs[m][cb], 0, 0, 0);
                }
            }
        }
        // no barrier here: loop-top __syncthreads() protects slab/sE before reuse
    }

    // ---- block end: deterministic cross-wave (wc) reduce, write partials ----
    __syncthreads();
    float* scr = (float*)&sbuf[0][0][0];   // [128][33] f32
    if (wc == 1) {
        #pragma unroll
        for (int m = 0; m < 4; m++)
            #pragma unroll
            for (int cb = 0; cb < 2; cb++)
                #pragma unroll
                for (int q = 0; q < 4; q++)
                    scr[(wr * 64 + m * 16 + l4 * 4 + q) * 33 + cb * 16 + l15] =
                        acc_cs[m][cb][q];
    }
    __syncthreads();
    if (wc == 0) {
        float* pc = pcls + (size_t)(itile * NCHUNK + jc) * 128 * NCLS;
        #pragma unroll
        for (int m = 0; m < 4; m++)
            #pragma unroll
            for (int cb = 0; cb < 2; cb++)
                #pragma unroll
                for (int q = 0; q < 4; q++) {
                    const int r = wr * 64 + m * 16 + l4 * 4 + q;
                    const int c = cb * 16 + l15;
                    pc[r * NCLS + c] = acc_cs[m][cb][q] + scr[r * 33 + c];
                }
    }
    if (t < 128) ppos[(size_t)(itile * NCHUNK + jc) * 128 + t] = spos[t];
}

// ---------------- kernel 4: per-anchor loss (8 lanes per anchor) ----------------
__global__ void reduce_kernel(const float* __restrict__ pcls, const float* __restrict__ ppos,
                              const int* __restrict__ counts, const int* __restrict__ labels,
                              float* __restrict__ loss_i, float* __restrict__ validf) {
    int tid = blockIdx.x * blockDim.x + threadIdx.x;
    int i  = tid >> 3;
    int cq = tid & 7;
    if (i >= B_SZ) return;
    int itile = i >> 7, ilocal = i & 127;

    f32x4 cs = (f32x4){0.f, 0.f, 0.f, 0.f};
    for (int ch = 0; ch < NCHUNK; ch++) {
        const float* p = pcls + ((size_t)(itile * NCHUNK + ch) * 128 + ilocal) * NCLS + cq * 4;
        f32x4 v = *(const f32x4*)p;
        cs = cs + v;
    }
    int labi = labels[i];
    float dpart = 0.0f;
    #pragma unroll
    for (int e = 0; e < 4; e++) {
        int c = cq * 4 + e;
        int cnt = counts[c] - (c == labi ? 1 : 0);
        if (cnt > 0) dpart += cs[e] / (float)cnt;
    }
    #pragma unroll
    for (int off = 1; off < 8; off <<= 1) dpart += __shfl_xor(dpart, off, 64);

    if (cq == 0) {
        float psum = 0.0f;
        for (int ch = 0; ch < NCHUNK; ch++)
            psum += ppos[(size_t)(itile * NCHUNK + ch) * 128 + ilocal];
        int P = counts[labi] - 1;
        bool valid = P > 0;
        float li = 0.0f;
        if (valid) li = logf(fmaxf(dpart, 1e-30f)) - psum / (float)max(P, 1);
        loss_i[i] = li;
        validf[i] = valid ? 1.0f : 0.0f;
    }
}

// ---------------- kernel 5: deterministic final reduction ----------------
__global__ void final_kernel(const float* __restrict__ loss_i, const float* __restrict__ validf,
                             float* __restrict__ out) {
    __shared__ float ssum[256];
    __shared__ float scnt[256];
    int t = threadIdx.x;
    float s = 0.0f, c = 0.0f;
    for (int i = t; i < B_SZ; i += 256) { s += loss_i[i]; c += validf[i]; }
    ssum[t] = s; scnt[t] = c;
    __syncthreads();
    #pragma unroll
    for (int off = 128; off > 0; off >>= 1) {
        if (t < off) { ssum[t] += ssum[t + off]; scnt[t] += scnt[t + off]; }
        __syncthreads();
    }
    if (t == 0) out[0] = (scnt[0] > 0.0f) ? ssum[0] / scnt[0] : 0.0f;
}

// ---------------- launch ----------------
extern "C" void kernel_launch(void* const* d_in, const int* in_sizes, int n_in,
                              void* d_out, int out_size, void* d_ws, size_t ws_size,
                              hipStream_t stream) {
    const float* feat   = (const float*)d_in[0];
    const int*   labels = (const int*)d_in[1];
    float*       out    = (float*)d_out;

    char* ws = (char*)d_ws;
    size_t off = 0;
    auto alloc = [&](size_t bytes) -> void* {
        void* p = ws + off;
        off = (off + bytes + 255) & ~(size_t)255;
        return p;
    };

    unsigned short* Fhl = (unsigned short*)alloc((size_t)B_SZ * 512 * 2);     // 8.4MB
    int*   counts = (int*)alloc((size_t)NCLS * 4);
    float* loss_i = (float*)alloc((size_t)B_SZ * 4);
    float* validf = (float*)alloc((size_t)B_SZ * 4);
    float* ppos   = (float*)alloc((size_t)512 * 128 * 4);                     // 256KB
    float* pcls   = (float*)alloc((size_t)512 * 128 * NCLS * 4);              // 8.4MB

    prep_kernel<<<B_SZ / 4, 256, 0, stream>>>(feat, Fhl);
    count_kernel<<<1, 256, 0, stream>>>(labels, counts);
    sim_kernel<<<512, 256, 0, stream>>>(Fhl, labels, pcls, ppos);
    reduce_kernel<<<B_SZ * 8 / 256, 256, 0, stream>>>(pcls, ppos, counts, labels, loss_i, validf);
    final_kernel<<<1, 256, 0, stream>>>(loss_i, validf, out);
}